// Round 5
// baseline (558.016 us; speedup 1.0000x reference)
//
#include <hip/hip_runtime.h>
#include <hip/hip_bf16.h>
#include <stdint.h>

typedef unsigned short u16;
typedef __bf16 bf16x8 __attribute__((ext_vector_type(8)));
typedef float f32x4 __attribute__((ext_vector_type(4)));

__device__ __forceinline__ u16 f2bf(float f) {
  union { float f; uint32_t u; } v; v.f = f;
  uint32_t u = v.u;
  return (u16)((u + 0x7FFFu + ((u >> 16) & 1u)) >> 16);
}

__device__ __forceinline__ f32x4 mfma16(bf16x8 a, bf16x8 b, f32x4 c) {
  return __builtin_amdgcn_mfma_f32_16x16x32_bf16(a, b, c, 0, 0, 0);
}

#define GLOBAL_TO_LDS16(g, l)                                                  \
  __builtin_amdgcn_global_load_lds(                                            \
      (const __attribute__((address_space(1))) void*)(g),                      \
      (__attribute__((address_space(3))) void*)(l), 16, 0, 0)

// T1: XCD-aware block swizzle (R4-verified WIN: FETCH 212->82MB, -14.5us on
// qkv<true>). Each XCD owns a contiguous chunk of logical blocks.
// Bijective iff nwg % 8 == 0 (true for all grids here).
__device__ __forceinline__ int xcd_swz(int lin, int nwg) {
  return (lin & 7) * (nwg >> 3) + (lin >> 3);
}

// ---------------- fused f32 -> bf16 conversion (x | qkv_w | proj_w) --------
__global__ void cvt_bf16_all(const float* __restrict__ x, u16* __restrict__ xb,
                             const float* __restrict__ qw, u16* __restrict__ qwb,
                             const float* __restrict__ pw, u16* __restrict__ pwb) {
  int blk = blockIdx.x;
  const float* src; u16* dst; int i;
  if (blk < 24576)        { src = x;  dst = xb;  i = blk * 256 + threadIdx.x; }
  else if (blk < 26304)   { src = qw; dst = qwb; i = (blk - 24576) * 256 + threadIdx.x; }
  else                    { src = pw; dst = pwb; i = (blk - 26304) * 256 + threadIdx.x; }
  float4 f = ((const float4*)src)[i];
  ushort4 o;
  o.x = f2bf(f.x); o.y = f2bf(f.y); o.z = f2bf(f.z); o.w = f2bf(f.w);
  ((ushort4*)dst)[i] = o;
}

// ---------------- QKV GEMM: 256x128 tile, 2-barrier loop ------------------
// Same verified sync structure / swizzle family as the 444us baseline; tile
// M doubled to 256 so per-K-tile drain+stage overhead amortizes over 2x FLOP
// (B-panel staging per FLOP halves; ds_read/MFMA ratio 0.5 -> 0.375).
// 4 waves in 2x2; wave tile 128x64 = acc[8][4]. LDS 48KB.
template <bool SWAP>
__global__ __launch_bounds__(256) void qkv_gemm(
    const u16* __restrict__ A, const u16* __restrict__ Bt, int nbase,
    u16* __restrict__ q, u16* __restrict__ k, u16* __restrict__ vT) {
  const int K = 768;
  __shared__ u16 As[256 * 64];
  __shared__ u16 Bs[128 * 64];
  int tid = threadIdx.x;
  int wave = tid >> 6, lane = tid & 63;
  int quad = lane >> 4, lrow = lane & 15;
  int lin = blockIdx.x + gridDim.x * blockIdx.y;
  int swz = xcd_swz(lin, gridDim.x * gridDim.y);
  int bx = swz % gridDim.x, by = swz / gridDim.x;
  int m0 = by * 256, n0 = nbase + bx * 128;
  int wm = wave >> 1, wn = wave & 1;

  const u16* asrc[8]; int adst[8];
#pragma unroll
  for (int s = 0; s < 8; s++) {
    int p = s * 256 + tid;
    int row = p >> 3, c = (p & 7) ^ (row & 7);
    asrc[s] = A + (size_t)(m0 + row) * K + c * 8;
    adst[s] = p * 8;
  }
  const u16* bsrc[4]; int bdst[4];
#pragma unroll
  for (int s = 0; s < 4; s++) {
    int p = s * 256 + tid;
    int row = p >> 3, c = (p & 7) ^ (row & 7);
    bsrc[s] = Bt + (size_t)(n0 + row) * K + c * 8;
    bdst[s] = p * 8;
  }
  f32x4 acc[8][4] = {};
  for (int k0 = 0; k0 < K; k0 += 64) {
#pragma unroll
    for (int s = 0; s < 8; s++) GLOBAL_TO_LDS16(asrc[s] + k0, As + adst[s]);
#pragma unroll
    for (int s = 0; s < 4; s++) GLOBAL_TO_LDS16(bsrc[s] + k0, Bs + bdst[s]);
    __syncthreads();
#pragma unroll
    for (int kk = 0; kk < 2; kk++) {
      bf16x8 am[8], bn[4];
#pragma unroll
      for (int m = 0; m < 8; m++) {
        int r = wm * 128 + m * 16 + lrow;
        am[m] = *(const bf16x8*)(As + r * 64 + ((((kk << 2) | quad) ^ (r & 7)) << 3));
      }
#pragma unroll
      for (int n = 0; n < 4; n++) {
        int r = wn * 64 + n * 16 + lrow;
        bn[n] = *(const bf16x8*)(Bs + r * 64 + ((((kk << 2) | quad) ^ (r & 7)) << 3));
      }
#pragma unroll
      for (int m = 0; m < 8; m++)
#pragma unroll
        for (int n = 0; n < 4; n++)
          acc[m][n] = SWAP ? mfma16(bn[n], am[m], acc[m][n])
                           : mfma16(am[m], bn[n], acc[m][n]);
    }
    __syncthreads();
  }
  if (SWAP) {
    // swapped: D rows (quad*4+reg) = feature, cols (lrow) = seq
    int t = n0 >= 768;
    float sc = t ? 1.0f : 0.125f;
    u16* dst = t ? k : q;
#pragma unroll
    for (int n = 0; n < 4; n++) {
      int f = (n0 - (t ? 768 : 0)) + wn * 64 + n * 16 + quad * 4;
      int h = f >> 6, d0 = f & 63;
#pragma unroll
      for (int m = 0; m < 8; m++) {
        int seqg = m0 + wm * 128 + m * 16 + lrow;
        int b = seqg >> 7, s = seqg & 127;
        ushort4 o;
        o.x = f2bf(acc[m][n][0] * sc); o.y = f2bf(acc[m][n][1] * sc);
        o.z = f2bf(acc[m][n][2] * sc); o.w = f2bf(acc[m][n][3] * sc);
        *(ushort4*)(dst + ((size_t)(b * 12 + h)) * 8192 + s * 64 + d0) = o;
      }
    }
  } else {
    // normal: D rows (quad*4+reg) = seq, cols (lrow) = feature
#pragma unroll
    for (int n = 0; n < 4; n++) {
      int nb = (n0 - 1536) + wn * 64 + n * 16 + lrow;
      int h = nb >> 6, d = nb & 63;
#pragma unroll
      for (int m = 0; m < 8; m++) {
        int seq0 = m0 + wm * 128 + m * 16 + quad * 4;
        int b = seq0 >> 7, s0 = seq0 & 127;
        ushort4 o;
        o.x = f2bf(acc[m][n][0]); o.y = f2bf(acc[m][n][1]);
        o.z = f2bf(acc[m][n][2]); o.w = f2bf(acc[m][n][3]);
        *(ushort4*)(vT + ((size_t)(b * 12 + h)) * 8192 + d * 128 + s0) = o;
      }
    }
  }
}

// ---------------- attention: one block per (b,h), 512 threads -------------
// (R4-verified structure + mask-load hoist: the 8 float4 mask loads are
//  issued at kernel top so their L2 latency hides under staging + QK^T,
//  instead of stalling serially between QK^T and softmax.)
__global__ __launch_bounds__(512) void attn_kernel(
    const u16* __restrict__ q, const u16* __restrict__ k, const u16* __restrict__ vT,
    const float* __restrict__ mask, const float* __restrict__ bias_table,
    u16* __restrict__ attn_out) {
  __shared__ u16 smem[2 * 128 * 64];  // qs | ks, then P[128][128]
  __shared__ u16 vTs[64 * 128];
  __shared__ float bias_s[255];
  u16* qs = smem;
  u16* ks = smem + 128 * 64;
  u16* ps = smem;
  int tid = threadIdx.x;
  int wave = tid >> 6, lane = tid & 63;
  int quad = lane >> 4, lrow = lane & 15;
  int bh = xcd_swz(blockIdx.x, gridDim.x);
  int b = bh / 12, h = bh - b * 12;
  int w = b & 63;
  int row = wave * 16 + lrow;  // this lane's query row

  // hoisted mask loads (independent of all LDS/staging)
  const float* mrow = mask + (size_t)w * 16384 + row * 128;
  float4 m4[8];
#pragma unroll
  for (int i = 0; i < 8; i++) m4[i] = *(const float4*)(mrow + i * 16 + quad * 4);

  if (tid < 255) bias_s[tid] = bias_table[tid * 12 + h];
  const u16* qg = q + (size_t)bh * 8192;
  const u16* kg = k + (size_t)bh * 8192;
  const u16* vg = vT + (size_t)bh * 8192;
#pragma unroll
  for (int s = 0; s < 2; s++) {
    int p = s * 512 + tid;
    int prow = p >> 3, c = (p & 7) ^ (prow & 7);
    GLOBAL_TO_LDS16(qg + prow * 64 + c * 8, qs + p * 8);
    GLOBAL_TO_LDS16(kg + prow * 64 + c * 8, ks + p * 8);
    int dd = p >> 4, cv = (p & 15) ^ (dd & 7);
    GLOBAL_TO_LDS16(vg + dd * 128 + cv * 8, vTs + p * 8);
  }
  __syncthreads();

  f32x4 sacc[8] = {};
#pragma unroll
  for (int kk = 0; kk < 2; kk++) {
    bf16x8 qf = *(const bf16x8*)(qs + row * 64 + ((((kk << 2) | quad) ^ (row & 7)) << 3));
#pragma unroll
    for (int i = 0; i < 8; i++) {
      int rk = i * 16 + lrow;
      bf16x8 kf = *(const bf16x8*)(ks + rk * 64 + ((((kk << 2) | quad) ^ (rk & 7)) << 3));
      sacc[i] = mfma16(kf, qf, sacc[i]);
    }
  }
#pragma unroll
  for (int i = 0; i < 8; i++) {
    int c0 = i * 16 + quad * 4;
    sacc[i][0] += bias_s[row - (c0 + 0) + 127] + m4[i].x;
    sacc[i][1] += bias_s[row - (c0 + 1) + 127] + m4[i].y;
    sacc[i][2] += bias_s[row - (c0 + 2) + 127] + m4[i].z;
    sacc[i][3] += bias_s[row - (c0 + 3) + 127] + m4[i].w;
  }
  float mx = sacc[0][0];
#pragma unroll
  for (int i = 0; i < 8; i++)
#pragma unroll
    for (int r = 0; r < 4; r++) mx = fmaxf(mx, sacc[i][r]);
  mx = fmaxf(mx, __shfl_xor(mx, 16, 64));
  mx = fmaxf(mx, __shfl_xor(mx, 32, 64));
  float sum = 0.f;
#pragma unroll
  for (int i = 0; i < 8; i++)
#pragma unroll
    for (int r = 0; r < 4; r++) {
      float e = __expf(sacc[i][r] - mx);
      sacc[i][r] = e;
      sum += e;
    }
  sum += __shfl_xor(sum, 16, 64);
  sum += __shfl_xor(sum, 32, 64);
  float inv = 1.f / sum;
  __syncthreads();
#pragma unroll
  for (int i = 0; i < 8; i++) {
    int chunk = i * 2 + (quad >> 1);
    int pos = chunk ^ (row & 7);
    ushort4 o;
    o.x = f2bf(sacc[i][0] * inv); o.y = f2bf(sacc[i][1] * inv);
    o.z = f2bf(sacc[i][2] * inv); o.w = f2bf(sacc[i][3] * inv);
    *(ushort4*)(ps + row * 128 + pos * 8 + (quad & 1) * 4) = o;
  }
  __syncthreads();

  f32x4 oacc[4] = {};
#pragma unroll
  for (int kk = 0; kk < 4; kk++) {
    bf16x8 pf = *(const bf16x8*)(ps + row * 128 + ((((kk << 2) | quad) ^ (row & 7)) << 3));
#pragma unroll
    for (int jd = 0; jd < 4; jd++) {
      int rd = jd * 16 + lrow;
      bf16x8 vf = *(const bf16x8*)(vTs + rd * 128 + ((((kk << 2) | quad) ^ (rd & 7)) << 3));
      oacc[jd] = mfma16(vf, pf, oacc[jd]);
    }
  }
#pragma unroll
  for (int jd = 0; jd < 4; jd++) {
    int d0 = jd * 16 + quad * 4;
    int seq = wave * 16 + lrow;
    ushort4 o;
    o.x = f2bf(oacc[jd][0]); o.y = f2bf(oacc[jd][1]);
    o.z = f2bf(oacc[jd][2]); o.w = f2bf(oacc[jd][3]);
    *(ushort4*)(attn_out + ((size_t)(b * 128 + seq)) * 768 + h * 64 + d0) = o;
  }
}

// ---------------- proj GEMM: 256x128 tile, 2-barrier loop -----------------
__global__ __launch_bounds__(256) void proj_gemm(
    const u16* __restrict__ A, const u16* __restrict__ Bt,
    const float* __restrict__ bias, float* __restrict__ out) {
  const int K = 768;
  __shared__ u16 As[256 * 64];
  __shared__ u16 Bs[128 * 64];
  int tid = threadIdx.x;
  int wave = tid >> 6, lane = tid & 63;
  int quad = lane >> 4, lrow = lane & 15;
  int lin = blockIdx.x + gridDim.x * blockIdx.y;
  int swz = xcd_swz(lin, gridDim.x * gridDim.y);
  int bx = swz % gridDim.x, by = swz / gridDim.x;
  int m0 = by * 256, n0 = bx * 128;
  int wm = wave >> 1, wn = wave & 1;

  const u16* asrc[8]; int adst[8];
#pragma unroll
  for (int s = 0; s < 8; s++) {
    int p = s * 256 + tid;
    int row = p >> 3, c = (p & 7) ^ (row & 7);
    asrc[s] = A + (size_t)(m0 + row) * K + c * 8;
    adst[s] = p * 8;
  }
  const u16* bsrc[4]; int bdst[4];
#pragma unroll
  for (int s = 0; s < 4; s++) {
    int p = s * 256 + tid;
    int row = p >> 3, c = (p & 7) ^ (row & 7);
    bsrc[s] = Bt + (size_t)(n0 + row) * K + c * 8;
    bdst[s] = p * 8;
  }
  f32x4 acc[8][4] = {};
  for (int k0 = 0; k0 < K; k0 += 64) {
#pragma unroll
    for (int s = 0; s < 8; s++) GLOBAL_TO_LDS16(asrc[s] + k0, As + adst[s]);
#pragma unroll
    for (int s = 0; s < 4; s++) GLOBAL_TO_LDS16(bsrc[s] + k0, Bs + bdst[s]);
    __syncthreads();
#pragma unroll
    for (int kk = 0; kk < 2; kk++) {
      bf16x8 am[8], bn[4];
#pragma unroll
      for (int m = 0; m < 8; m++) {
        int r = wm * 128 + m * 16 + lrow;
        am[m] = *(const bf16x8*)(As + r * 64 + ((((kk << 2) | quad) ^ (r & 7)) << 3));
      }
#pragma unroll
      for (int n = 0; n < 4; n++) {
        int r = wn * 64 + n * 16 + lrow;
        bn[n] = *(const bf16x8*)(Bs + r * 64 + ((((kk << 2) | quad) ^ (r & 7)) << 3));
      }
#pragma unroll
      for (int m = 0; m < 8; m++)
#pragma unroll
        for (int n = 0; n < 4; n++)
          acc[m][n] = mfma16(bn[n], am[m], acc[m][n]);
    }
    __syncthreads();
  }
#pragma unroll
  for (int n = 0; n < 4; n++) {
    int nb = n0 + wn * 64 + n * 16 + quad * 4;
    float4 b4 = *(const float4*)(bias + nb);
#pragma unroll
    for (int m = 0; m < 8; m++) {
      int mr = m0 + wm * 128 + m * 16 + lrow;
      float4 o;
      o.x = acc[m][n][0] + b4.x; o.y = acc[m][n][1] + b4.y;
      o.z = acc[m][n][2] + b4.z; o.w = acc[m][n][3] + b4.w;
      *(float4*)(out + (size_t)mr * 768 + nb) = o;
    }
  }
}

extern "C" void kernel_launch(void* const* d_in, const int* in_sizes, int n_in,
                              void* d_out, int out_size, void* d_ws, size_t ws_size,
                              hipStream_t stream) {
  const float* x          = (const float*)d_in[0];
  const float* mask       = (const float*)d_in[1];
  const float* qkv_w      = (const float*)d_in[2];
  const float* bias_table = (const float*)d_in[3];
  const float* proj_w     = (const float*)d_in[4];
  const float* proj_b     = (const float*)d_in[5];
  float* out = (float*)d_out;
  char* ws = (char*)d_ws;
  u16* q_b    = (u16*)(ws);                    // 50331648
  u16* k_b    = (u16*)(ws + 50331648);         // 50331648
  u16* vT_b   = (u16*)(ws + 100663296);        // 50331648
  u16* x_b    = (u16*)(ws + 150994944);        // 50331648 (x bf16, reused as attn_out)
  u16* qw_b   = (u16*)(ws + 201326592);        // 3538944
  u16* pw_b   = (u16*)(ws + 204865536);        // 1179648
  u16* attn_b = x_b;

  cvt_bf16_all<<<26880, 256, 0, stream>>>(x, x_b, qkv_w, qw_b, proj_w, pw_b);
  qkv_gemm<true><<<dim3(12, 128), 256, 0, stream>>>(x_b, qw_b, 0, q_b, k_b, vT_b);
  qkv_gemm<false><<<dim3(6, 128), 256, 0, stream>>>(x_b, qw_b, 1536, q_b, k_b, vT_b);
  attn_kernel<<<3072, 512, 0, stream>>>(q_b, k_b, vT_b, mask, bias_table, attn_b);
  proj_gemm<<<dim3(6, 128), 256, 0, stream>>>(attn_b, pw_b, proj_b, out);
}

// Round 6
// 409.882 us; speedup vs baseline: 1.3614x; 1.3614x over previous
//
#include <hip/hip_runtime.h>
#include <hip/hip_bf16.h>
#include <stdint.h>

typedef unsigned short u16;
typedef __bf16 bf16x8 __attribute__((ext_vector_type(8)));
typedef float f32x4 __attribute__((ext_vector_type(4)));

__device__ __forceinline__ u16 f2bf(float f) {
  union { float f; uint32_t u; } v; v.f = f;
  uint32_t u = v.u;
  return (u16)((u + 0x7FFFu + ((u >> 16) & 1u)) >> 16);
}

__device__ __forceinline__ f32x4 mfma16(bf16x8 a, bf16x8 b, f32x4 c) {
  return __builtin_amdgcn_mfma_f32_16x16x32_bf16(a, b, c, 0, 0, 0);
}

#define GLOBAL_TO_LDS16(g, l)                                                  \
  __builtin_amdgcn_global_load_lds(                                            \
      (const __attribute__((address_space(1))) void*)(g),                      \
      (__attribute__((address_space(3))) void*)(l), 16, 0, 0)

// T1: XCD-aware block swizzle (R4-verified WIN: FETCH 212->82MB on qkv<true>).
// Bijective iff nwg % 8 == 0 (true for all grids here).
__device__ __forceinline__ int xcd_swz(int lin, int nwg) {
  return (lin & 7) * (nwg >> 3) + (lin >> 3);
}

// ---------------- fused f32 -> bf16 conversion (x | qkv_w | proj_w) --------
__global__ void cvt_bf16_all(const float* __restrict__ x, u16* __restrict__ xb,
                             const float* __restrict__ qw, u16* __restrict__ qwb,
                             const float* __restrict__ pw, u16* __restrict__ pwb) {
  int blk = blockIdx.x;
  const float* src; u16* dst; int i;
  if (blk < 24576)        { src = x;  dst = xb;  i = blk * 256 + threadIdx.x; }
  else if (blk < 26304)   { src = qw; dst = qwb; i = (blk - 24576) * 256 + threadIdx.x; }
  else                    { src = pw; dst = pwb; i = (blk - 26304) * 256 + threadIdx.x; }
  float4 f = ((const float4*)src)[i];
  ushort4 o;
  o.x = f2bf(f.x); o.y = f2bf(f.y); o.z = f2bf(f.z); o.w = f2bf(f.w);
  ((ushort4*)dst)[i] = o;
}

// ---------------- QKV GEMM: 256x128 tile, 512 threads, 2-barrier loop -----
// R5 lesson: amortize per-K-tile overhead by growing the BLOCK, not the wave.
// 8 waves (4m x 2n), per-wave tile stays 64x64 (acc[4][4], ~88 VGPR like the
// verified 128^2 kernel). A staged once per 2x FLOP; barrier drains per FLOP
// halve; LDS 48KB -> 3 blocks/CU (24 waves/CU vs 20).
template <bool SWAP>
__global__ __launch_bounds__(512) void qkv_gemm(
    const u16* __restrict__ A, const u16* __restrict__ Bt, int nbase,
    u16* __restrict__ q, u16* __restrict__ k, u16* __restrict__ vT) {
  const int K = 768;
  __shared__ u16 As[256 * 64];
  __shared__ u16 Bs[128 * 64];
  int tid = threadIdx.x;
  int wave = tid >> 6, lane = tid & 63;
  int quad = lane >> 4, lrow = lane & 15;
  int lin = blockIdx.x + gridDim.x * blockIdx.y;
  int swz = xcd_swz(lin, gridDim.x * gridDim.y);
  int bx = swz % gridDim.x, by = swz / gridDim.x;
  int m0 = by * 256, n0 = nbase + bx * 128;
  int wm = wave >> 1, wn = wave & 1;     // 4 x 2 wave grid, 64x64 per wave

  const u16* asrc[4]; int adst[4];
#pragma unroll
  for (int s = 0; s < 4; s++) {
    int p = s * 512 + tid;               // [0, 2048) chunks of As
    int row = p >> 3, c = (p & 7) ^ (row & 7);
    asrc[s] = A + (size_t)(m0 + row) * K + c * 8;
    adst[s] = p * 8;
  }
  const u16* bsrc[2]; int bdst[2];
#pragma unroll
  for (int s = 0; s < 2; s++) {
    int p = s * 512 + tid;               // [0, 1024) chunks of Bs
    int row = p >> 3, c = (p & 7) ^ (row & 7);
    bsrc[s] = Bt + (size_t)(n0 + row) * K + c * 8;
    bdst[s] = p * 8;
  }
  f32x4 acc[4][4] = {};
  for (int k0 = 0; k0 < K; k0 += 64) {
#pragma unroll
    for (int s = 0; s < 4; s++) GLOBAL_TO_LDS16(asrc[s] + k0, As + adst[s]);
#pragma unroll
    for (int s = 0; s < 2; s++) GLOBAL_TO_LDS16(bsrc[s] + k0, Bs + bdst[s]);
    __syncthreads();
#pragma unroll
    for (int kk = 0; kk < 2; kk++) {
      bf16x8 am[4], bn[4];
#pragma unroll
      for (int i = 0; i < 4; i++) {
        int r = wm * 64 + i * 16 + lrow;
        am[i] = *(const bf16x8*)(As + r * 64 + ((((kk << 2) | quad) ^ (r & 7)) << 3));
      }
#pragma unroll
      for (int j = 0; j < 4; j++) {
        int r = wn * 64 + j * 16 + lrow;
        bn[j] = *(const bf16x8*)(Bs + r * 64 + ((((kk << 2) | quad) ^ (r & 7)) << 3));
      }
#pragma unroll
      for (int i = 0; i < 4; i++)
#pragma unroll
        for (int j = 0; j < 4; j++)
          acc[i][j] = SWAP ? mfma16(bn[j], am[i], acc[i][j])
                           : mfma16(am[i], bn[j], acc[i][j]);
    }
    __syncthreads();
  }
  if (SWAP) {
    // swapped: D rows (quad*4+reg) = feature, cols (lrow) = seq
    int t = n0 >= 768;
    float sc = t ? 1.0f : 0.125f;
    u16* dst = t ? k : q;
#pragma unroll
    for (int j = 0; j < 4; j++) {
      int f = (n0 - (t ? 768 : 0)) + wn * 64 + j * 16 + quad * 4;
      int h = f >> 6, d0 = f & 63;
#pragma unroll
      for (int i = 0; i < 4; i++) {
        int seqg = m0 + wm * 64 + i * 16 + lrow;
        int b = seqg >> 7, s = seqg & 127;
        ushort4 o;
        o.x = f2bf(acc[i][j][0] * sc); o.y = f2bf(acc[i][j][1] * sc);
        o.z = f2bf(acc[i][j][2] * sc); o.w = f2bf(acc[i][j][3] * sc);
        *(ushort4*)(dst + ((size_t)(b * 12 + h)) * 8192 + s * 64 + d0) = o;
      }
    }
  } else {
    // normal: D rows (quad*4+reg) = seq, cols (lrow) = feature
#pragma unroll
    for (int j = 0; j < 4; j++) {
      int f = (n0 - 1536) + wn * 64 + j * 16 + lrow;
      int h = f >> 6, d = f & 63;
#pragma unroll
      for (int i = 0; i < 4; i++) {
        int seqg = m0 + wm * 64 + i * 16 + quad * 4;
        int b = seqg >> 7, s0 = seqg & 127;
        ushort4 o;
        o.x = f2bf(acc[i][j][0]); o.y = f2bf(acc[i][j][1]);
        o.z = f2bf(acc[i][j][2]); o.w = f2bf(acc[i][j][3]);
        *(ushort4*)(vT + ((size_t)(b * 12 + h)) * 8192 + d * 128 + s0) = o;
      }
    }
  }
}

// ---------------- attention: one block per (b,h), 512 threads -------------
// (R4-verified structure + mask-load hoist, correctness-verified in R5 run)
__global__ __launch_bounds__(512) void attn_kernel(
    const u16* __restrict__ q, const u16* __restrict__ k, const u16* __restrict__ vT,
    const float* __restrict__ mask, const float* __restrict__ bias_table,
    u16* __restrict__ attn_out) {
  __shared__ u16 smem[2 * 128 * 64];  // qs | ks, then P[128][128]
  __shared__ u16 vTs[64 * 128];
  __shared__ float bias_s[255];
  u16* qs = smem;
  u16* ks = smem + 128 * 64;
  u16* ps = smem;
  int tid = threadIdx.x;
  int wave = tid >> 6, lane = tid & 63;
  int quad = lane >> 4, lrow = lane & 15;
  int bh = xcd_swz(blockIdx.x, gridDim.x);
  int b = bh / 12, h = bh - b * 12;
  int w = b & 63;
  int row = wave * 16 + lrow;  // this lane's query row

  // hoisted mask loads (independent of all LDS/staging)
  const float* mrow = mask + (size_t)w * 16384 + row * 128;
  float4 m4[8];
#pragma unroll
  for (int i = 0; i < 8; i++) m4[i] = *(const float4*)(mrow + i * 16 + quad * 4);

  if (tid < 255) bias_s[tid] = bias_table[tid * 12 + h];
  const u16* qg = q + (size_t)bh * 8192;
  const u16* kg = k + (size_t)bh * 8192;
  const u16* vg = vT + (size_t)bh * 8192;
#pragma unroll
  for (int s = 0; s < 2; s++) {
    int p = s * 512 + tid;
    int prow = p >> 3, c = (p & 7) ^ (prow & 7);
    GLOBAL_TO_LDS16(qg + prow * 64 + c * 8, qs + p * 8);
    GLOBAL_TO_LDS16(kg + prow * 64 + c * 8, ks + p * 8);
    int dd = p >> 4, cv = (p & 15) ^ (dd & 7);
    GLOBAL_TO_LDS16(vg + dd * 128 + cv * 8, vTs + p * 8);
  }
  __syncthreads();

  f32x4 sacc[8] = {};
#pragma unroll
  for (int kk = 0; kk < 2; kk++) {
    bf16x8 qf = *(const bf16x8*)(qs + row * 64 + ((((kk << 2) | quad) ^ (row & 7)) << 3));
#pragma unroll
    for (int i = 0; i < 8; i++) {
      int rk = i * 16 + lrow;
      bf16x8 kf = *(const bf16x8*)(ks + rk * 64 + ((((kk << 2) | quad) ^ (rk & 7)) << 3));
      sacc[i] = mfma16(kf, qf, sacc[i]);
    }
  }
#pragma unroll
  for (int i = 0; i < 8; i++) {
    int c0 = i * 16 + quad * 4;
    sacc[i][0] += bias_s[row - (c0 + 0) + 127] + m4[i].x;
    sacc[i][1] += bias_s[row - (c0 + 1) + 127] + m4[i].y;
    sacc[i][2] += bias_s[row - (c0 + 2) + 127] + m4[i].z;
    sacc[i][3] += bias_s[row - (c0 + 3) + 127] + m4[i].w;
  }
  float mx = sacc[0][0];
#pragma unroll
  for (int i = 0; i < 8; i++)
#pragma unroll
    for (int r = 0; r < 4; r++) mx = fmaxf(mx, sacc[i][r]);
  mx = fmaxf(mx, __shfl_xor(mx, 16, 64));
  mx = fmaxf(mx, __shfl_xor(mx, 32, 64));
  float sum = 0.f;
#pragma unroll
  for (int i = 0; i < 8; i++)
#pragma unroll
    for (int r = 0; r < 4; r++) {
      float e = __expf(sacc[i][r] - mx);
      sacc[i][r] = e;
      sum += e;
    }
  sum += __shfl_xor(sum, 16, 64);
  sum += __shfl_xor(sum, 32, 64);
  float inv = 1.f / sum;
  __syncthreads();
#pragma unroll
  for (int i = 0; i < 8; i++) {
    int chunk = i * 2 + (quad >> 1);
    int pos = chunk ^ (row & 7);
    ushort4 o;
    o.x = f2bf(sacc[i][0] * inv); o.y = f2bf(sacc[i][1] * inv);
    o.z = f2bf(sacc[i][2] * inv); o.w = f2bf(sacc[i][3] * inv);
    *(ushort4*)(ps + row * 128 + pos * 8 + (quad & 1) * 4) = o;
  }
  __syncthreads();

  f32x4 oacc[4] = {};
#pragma unroll
  for (int kk = 0; kk < 4; kk++) {
    bf16x8 pf = *(const bf16x8*)(ps + row * 128 + ((((kk << 2) | quad) ^ (row & 7)) << 3));
#pragma unroll
    for (int jd = 0; jd < 4; jd++) {
      int rd = jd * 16 + lrow;
      bf16x8 vf = *(const bf16x8*)(vTs + rd * 128 + ((((kk << 2) | quad) ^ (rd & 7)) << 3));
      oacc[jd] = mfma16(vf, pf, oacc[jd]);
    }
  }
#pragma unroll
  for (int jd = 0; jd < 4; jd++) {
    int d0 = jd * 16 + quad * 4;
    int seq = wave * 16 + lrow;
    ushort4 o;
    o.x = f2bf(oacc[jd][0]); o.y = f2bf(oacc[jd][1]);
    o.z = f2bf(oacc[jd][2]); o.w = f2bf(oacc[jd][3]);
    *(ushort4*)(attn_out + ((size_t)(b * 128 + seq)) * 768 + h * 64 + d0) = o;
  }
}

// ---------------- proj GEMM: 256x128 tile, 512 threads, 2-barrier loop ----
__global__ __launch_bounds__(512) void proj_gemm(
    const u16* __restrict__ A, const u16* __restrict__ Bt,
    const float* __restrict__ bias, float* __restrict__ out) {
  const int K = 768;
  __shared__ u16 As[256 * 64];
  __shared__ u16 Bs[128 * 64];
  int tid = threadIdx.x;
  int wave = tid >> 6, lane = tid & 63;
  int quad = lane >> 4, lrow = lane & 15;
  int lin = blockIdx.x + gridDim.x * blockIdx.y;
  int swz = xcd_swz(lin, gridDim.x * gridDim.y);
  int bx = swz % gridDim.x, by = swz / gridDim.x;
  int m0 = by * 256, n0 = bx * 128;
  int wm = wave >> 1, wn = wave & 1;

  const u16* asrc[4]; int adst[4];
#pragma unroll
  for (int s = 0; s < 4; s++) {
    int p = s * 512 + tid;
    int row = p >> 3, c = (p & 7) ^ (row & 7);
    asrc[s] = A + (size_t)(m0 + row) * K + c * 8;
    adst[s] = p * 8;
  }
  const u16* bsrc[2]; int bdst[2];
#pragma unroll
  for (int s = 0; s < 2; s++) {
    int p = s * 512 + tid;
    int row = p >> 3, c = (p & 7) ^ (row & 7);
    bsrc[s] = Bt + (size_t)(n0 + row) * K + c * 8;
    bdst[s] = p * 8;
  }
  f32x4 acc[4][4] = {};
  for (int k0 = 0; k0 < K; k0 += 64) {
#pragma unroll
    for (int s = 0; s < 4; s++) GLOBAL_TO_LDS16(asrc[s] + k0, As + adst[s]);
#pragma unroll
    for (int s = 0; s < 2; s++) GLOBAL_TO_LDS16(bsrc[s] + k0, Bs + bdst[s]);
    __syncthreads();
#pragma unroll
    for (int kk = 0; kk < 2; kk++) {
      bf16x8 am[4], bn[4];
#pragma unroll
      for (int i = 0; i < 4; i++) {
        int r = wm * 64 + i * 16 + lrow;
        am[i] = *(const bf16x8*)(As + r * 64 + ((((kk << 2) | quad) ^ (r & 7)) << 3));
      }
#pragma unroll
      for (int j = 0; j < 4; j++) {
        int r = wn * 64 + j * 16 + lrow;
        bn[j] = *(const bf16x8*)(Bs + r * 64 + ((((kk << 2) | quad) ^ (r & 7)) << 3));
      }
#pragma unroll
      for (int i = 0; i < 4; i++)
#pragma unroll
        for (int j = 0; j < 4; j++)
          acc[i][j] = mfma16(bn[j], am[i], acc[i][j]);
    }
    __syncthreads();
  }
#pragma unroll
  for (int j = 0; j < 4; j++) {
    int nb = n0 + wn * 64 + j * 16 + quad * 4;
    float4 b4 = *(const float4*)(bias + nb);
#pragma unroll
    for (int i = 0; i < 4; i++) {
      int mr = m0 + wm * 64 + i * 16 + lrow;
      float4 o;
      o.x = acc[i][j][0] + b4.x; o.y = acc[i][j][1] + b4.y;
      o.z = acc[i][j][2] + b4.z; o.w = acc[i][j][3] + b4.w;
      *(float4*)(out + (size_t)mr * 768 + nb) = o;
    }
  }
}

extern "C" void kernel_launch(void* const* d_in, const int* in_sizes, int n_in,
                              void* d_out, int out_size, void* d_ws, size_t ws_size,
                              hipStream_t stream) {
  const float* x          = (const float*)d_in[0];
  const float* mask       = (const float*)d_in[1];
  const float* qkv_w      = (const float*)d_in[2];
  const float* bias_table = (const float*)d_in[3];
  const float* proj_w     = (const float*)d_in[4];
  const float* proj_b     = (const float*)d_in[5];
  float* out = (float*)d_out;
  char* ws = (char*)d_ws;
  u16* q_b    = (u16*)(ws);                    // 50331648
  u16* k_b    = (u16*)(ws + 50331648);         // 50331648
  u16* vT_b   = (u16*)(ws + 100663296);        // 50331648
  u16* x_b    = (u16*)(ws + 150994944);        // 50331648 (x bf16, reused as attn_out)
  u16* qw_b   = (u16*)(ws + 201326592);        // 3538944
  u16* pw_b   = (u16*)(ws + 204865536);        // 1179648
  u16* attn_b = x_b;

  cvt_bf16_all<<<26880, 256, 0, stream>>>(x, x_b, qkv_w, qw_b, proj_w, pw_b);
  qkv_gemm<true><<<dim3(12, 128), 512, 0, stream>>>(x_b, qw_b, 0, q_b, k_b, vT_b);
  qkv_gemm<false><<<dim3(6, 128), 512, 0, stream>>>(x_b, qw_b, 1536, q_b, k_b, vT_b);
  attn_kernel<<<3072, 512, 0, stream>>>(q_b, k_b, vT_b, mask, bias_table, attn_b);
  proj_gemm<<<dim3(6, 128), 512, 0, stream>>>(attn_b, pw_b, proj_b, out);
}